// Round 5
// baseline (1238.448 us; speedup 1.0000x reference)
//
#include <hip/hip_runtime.h>
#include <math.h>

#define N_TOK 8192
#define DIM   768
#define MEMN  10000
#define MEMP  10240            // padded to 40*256
#define TQ    32
#define TM    256
#define NSPLIT 2
#define TILES_PER_SPLIT 20

constexpr float SCALE = 0.036084391824351615f;  // 1/sqrt(768)

typedef short bf16x8 __attribute__((ext_vector_type(8)));
typedef float f32x4  __attribute__((ext_vector_type(4)));

__device__ __forceinline__ unsigned short f2bf(float f) {
    unsigned u = __float_as_uint(f);
    unsigned r = (u + 0x7fffu + ((u >> 16) & 1u)) >> 16;   // RTN-even
    return (unsigned short)r;
}

// ---------------------------------------------------------------------------
// memF: fragment-linear bf16 layout of mem for phase 1 (QK^T B-operand).
// slot(mb, kc, l16, quad, j) = mem[mb*16 + l16][kc*32 + quad*8 + j]
// offset (ushorts) = (mb*24 + kc)*512 + (l16*4 + quad)*8
// ---------------------------------------------------------------------------
__global__ void cvt_memF(const float* __restrict__ mem, unsigned short* __restrict__ dst)
{
    const int mb = blockIdx.x;                       // 0..639
    const bool zero = (mb >= MEMN / 16);             // 625 exact blocks valid
#pragma unroll
    for (int it = 0; it < 6; ++it) {
        const int s   = it * 256 + threadIdx.x;      // 0..1535
        const int kc  = s >> 6;
        const int r   = s & 63;
        const int l16 = r >> 2, q = r & 3;
        unsigned short o[8];
        if (!zero) {
            const float* src = &mem[(size_t)(mb * 16 + l16) * DIM + kc * 32 + q * 8];
            float4 v0 = *(const float4*)src;
            float4 v1 = *(const float4*)(src + 4);
            o[0] = f2bf(v0.x); o[1] = f2bf(v0.y); o[2] = f2bf(v0.z); o[3] = f2bf(v0.w);
            o[4] = f2bf(v1.x); o[5] = f2bf(v1.y); o[6] = f2bf(v1.z); o[7] = f2bf(v1.w);
        } else {
#pragma unroll
            for (int j = 0; j < 8; ++j) o[j] = 0;
        }
        *(uint4*)&dst[((size_t)mb * 24 + kc) * 512 + r * 8] = *(const uint4*)o;
    }
}

// ---------------------------------------------------------------------------
// Q fp32 -> bf16 (row-major, same layout)
// ---------------------------------------------------------------------------
__global__ void cvt_qH(const float* __restrict__ q, unsigned short* __restrict__ dst)
{
    const size_t i = ((size_t)blockIdx.x * 256 + threadIdx.x) * 4;
    float4 v = *(const float4*)&q[i];
    ushort4 o;
    o.x = f2bf(v.x); o.y = f2bf(v.y); o.z = f2bf(v.z); o.w = f2bf(v.w);
    *(ushort4*)&dst[i] = o;
}

// ---------------------------------------------------------------------------
// memS: fragment-linear transposed layout for phase 2 (PV B-operand).
// slot(db, mc, l16, quad, j) = mem[mc*32 + quad*8 + j][db*16 + l16]  (0 if m>=10000)
// offset (ushorts) = (db*320 + mc)*512 + (l16*4 + quad)*8
// ---------------------------------------------------------------------------
__global__ void cvt_memS(const float* __restrict__ mem, unsigned short* __restrict__ dst)
{
    __shared__ float T[32][65];
    const int mc = blockIdx.x;              // m-chunk of 32
    const int d0 = blockIdx.y * 64;         // d base
    const int tx = threadIdx.x & 63;        // d within 64
    const int ty = threadIdx.x >> 6;        // 0..3
#pragma unroll
    for (int i = 0; i < 8; ++i) {
        const int row = ty + 4 * i;                  // 0..31
        const int m   = mc * 32 + row;
        T[row][tx] = (m < MEMN) ? mem[(size_t)m * DIM + d0 + tx] : 0.f;
    }
    __syncthreads();
    const int dbl = threadIdx.x >> 6;       // local 16-d block 0..3
    const int r   = threadIdx.x & 63;
    const int l16 = r >> 2, q = r & 3;
    unsigned short o[8];
#pragma unroll
    for (int j = 0; j < 8; ++j) o[j] = f2bf(T[q * 8 + j][dbl * 16 + l16]);
    *(uint4*)&dst[((size_t)(d0 / 16 + dbl) * 320 + mc) * 512 + r * 8] = *(const uint4*)o;
}

// ---------------------------------------------------------------------------
// W12T bf16 [768 n][1536 k]
// ---------------------------------------------------------------------------
__global__ void prep_w12T(const float* __restrict__ w1, unsigned short* __restrict__ wt)
{
    __shared__ float T[32][33];
    const int kb = blockIdx.x * 32, nb = blockIdx.y * 32;
    const int tx = threadIdx.x & 31, ty = threadIdx.x >> 5;
#pragma unroll
    for (int i = 0; i < 4; ++i) {
        int k = kb + ty + 8 * i;
        float v = w1[(size_t)(768 + k) * DIM + nb + tx];
        if (kb < 768) v += w1[(size_t)k * DIM + nb + tx];
        T[ty + 8 * i][tx] = v;
    }
    __syncthreads();
#pragma unroll
    for (int i = 0; i < 4; ++i) {
        int n = nb + ty + 8 * i;
        wt[(size_t)n * 1536 + kb + tx] = f2bf(T[tx][ty + 8 * i]);
    }
}

// ---------------------------------------------------------------------------
// W2T bf16 [768 n][768 k] = w2[k][n]
// ---------------------------------------------------------------------------
__global__ void prep_w2T(const float* __restrict__ w2, unsigned short* __restrict__ wt)
{
    __shared__ float T[32][33];
    const int kb = blockIdx.x * 32, nb = blockIdx.y * 32;
    const int tx = threadIdx.x & 31, ty = threadIdx.x >> 5;
#pragma unroll
    for (int i = 0; i < 4; ++i)
        T[ty + 8 * i][tx] = w2[(size_t)(kb + ty + 8 * i) * DIM + nb + tx];
    __syncthreads();
#pragma unroll
    for (int i = 0; i < 4; ++i)
        wt[(size_t)(nb + ty + 8 * i) * DIM + kb + tx] = f2bf(T[tx][ty + 8 * i]);
}

// ---------------------------------------------------------------------------
// Fused MFMA attention. Round-12:
//  - NSPLIT back to 2 (NSPLIT sweep 2/4/8 = 762/797/877 us: atomic epilogue
//    traffic scales with splits, cache hit rate doesn't change. 2 is optimal.)
//  - phase-1 software pipeline deepened to distance-6 at ZERO register cost:
//    per-wave m-strip 32 -> 16 rows x two passes (sacc 16->8 regs), single
//    B-stream pb[6] rotation (24 regs vs old 16). Effective per-wave MLP in
//    phase 1: 2 -> 6, targeting the measured ~1.3 MLP/SIMD stall floor.
//  - half-1 prologue loads issue right after barrier A, hiding under
//    half-0's exp VALU.
// ---------------------------------------------------------------------------
__global__ __launch_bounds__(512, 4)
void attn_mfma(const unsigned short* __restrict__ qH, const unsigned short* __restrict__ memF,
               const unsigned short* __restrict__ memS,
               float* __restrict__ retrRaw, float* __restrict__ Lvec)
{
    __shared__ __align__(16) unsigned short Qs[32 * 768];   // 48 KB, xor-swizzled
    __shared__ __align__(16) unsigned short Ps[32 * 256];   // 16 KB, xor-swizzled

    const int tid    = threadIdx.x;
    const int w      = tid >> 6;         // wave 0..7
    const int lane   = tid & 63;
    const int quad   = lane >> 4;        // 0..3
    const int l16    = lane & 15;
    const int fr     = ((l16 << 2) | quad) << 3;   // fragment-linear lane offset (ushorts)

    const int lb    = blockIdx.x + gridDim.x * blockIdx.y;   // 0..511
    const int split = (lb >> 2) & 1;
    const int qi    = ((lb >> 3) << 2) | (lb & 3);           // 0..255
    const int q0    = qi * TQ;

    const int dbase = w * 96;            // phase-2 d-strip per wave

    // ---- stage Q tile (bf16, swizzled) once ----
    {
        const int qr  = tid >> 4;            // 0..31
        const int db0 = tid & 15;
        const unsigned short* src = qH + (size_t)(q0 + qr) * DIM;
        const int sw = qr & 7;
#pragma unroll
        for (int i = 0; i < 6; ++i) {
            int db = db0 + i * 16;           // 0..95 (blocks of 8 bf16)
            uint4 v = *(const uint4*)&src[db * 8];
            *(uint4*)&Qs[qr * 768 + ((db ^ sw) << 3)] = v;
        }
    }
    __syncthreads();

    f32x4 oacc[2][6];
#pragma unroll
    for (int a = 0; a < 2; ++a)
#pragma unroll
        for (int b = 0; b < 6; ++b) oacc[a][b] = (f32x4){0.f, 0.f, 0.f, 0.f};
    float lsum[2][4] = {{0.f, 0.f, 0.f, 0.f}, {0.f, 0.f, 0.f, 0.f}};

    const int xsw = l16 & 7;

    for (int st = 0; st < TILES_PER_SPLIT; ++st) {
        const int m0  = (split * TILES_PER_SPLIT + st) * TM;
        const int mc0 = m0 >> 5;                          // m-chunk base for phase 2

        // ============ phase 1, half 0: m-local [w*16, w*16+16) ============
        bf16x8 pb[6];
        const unsigned short* fb0 = memF + ((size_t)(m0 >> 4) + w) * 12288 + fr;
#pragma unroll
        for (int i = 0; i < 6; ++i) pb[i] = *(const bf16x8*)(fb0 + i * 512);

        f32x4 s00 = (f32x4){0.f, 0.f, 0.f, 0.f};
        f32x4 s01 = (f32x4){0.f, 0.f, 0.f, 0.f};
#pragma unroll
        for (int ks = 0; ks < 24; ++ks) {
            const int xq = (((ks << 2) + quad) ^ xsw) << 3;
            bf16x8 a0 = *(const bf16x8*)&Qs[l16 * 768 + xq];
            bf16x8 a1 = *(const bf16x8*)&Qs[(16 + l16) * 768 + xq];
            s00 = __builtin_amdgcn_mfma_f32_16x16x32_bf16(a0, pb[ks % 6], s00, 0, 0, 0);
            s01 = __builtin_amdgcn_mfma_f32_16x16x32_bf16(a1, pb[ks % 6], s01, 0, 0, 0);
            if (ks < 18) pb[ks % 6] = *(const bf16x8*)(fb0 + (ks + 6) * 512);
        }

        __syncthreads();   // barrier A: all waves done reading previous tile's Ps

        // ---- half-1 prologue loads (overlap with exp below) ----
        const unsigned short* fb1 = memF + ((size_t)(m0 >> 4) + 8 + w) * 12288 + fr;
#pragma unroll
        for (int i = 0; i < 6; ++i) pb[i] = *(const bf16x8*)(fb1 + i * 512);

        // ---- exp + P->LDS for half 0 ----
        {
            const int mloc = w * 16 + l16;               // 0..127
            const bool ok  = (m0 + mloc) < MEMN;
#pragma unroll
            for (int r = 0; r < 4; ++r) {
                float p0 = ok ? __expf(s00[r] * SCALE) : 0.f;
                const int qa = quad * 4 + r;
                lsum[0][r] += p0;
                Ps[qa * 256 + (((mloc >> 3) ^ (qa & 7)) << 3) + (mloc & 7)] = f2bf(p0);
                float p1 = ok ? __expf(s01[r] * SCALE) : 0.f;
                const int qb = 16 + quad * 4 + r;
                lsum[1][r] += p1;
                Ps[qb * 256 + (((mloc >> 3) ^ (qb & 7)) << 3) + (mloc & 7)] = f2bf(p1);
            }
        }

        // ============ phase 1, half 1: m-local [128 + w*16, +16) ============
        f32x4 s10 = (f32x4){0.f, 0.f, 0.f, 0.f};
        f32x4 s11 = (f32x4){0.f, 0.f, 0.f, 0.f};
#pragma unroll
        for (int ks = 0; ks < 24; ++ks) {
            const int xq = (((ks << 2) + quad) ^ xsw) << 3;
            bf16x8 a0 = *(const bf16x8*)&Qs[l16 * 768 + xq];
            bf16x8 a1 = *(const bf16x8*)&Qs[(16 + l16) * 768 + xq];
            s10 = __builtin_amdgcn_mfma_f32_16x16x32_bf16(a0, pb[ks % 6], s10, 0, 0, 0);
            s11 = __builtin_amdgcn_mfma_f32_16x16x32_bf16(a1, pb[ks % 6], s11, 0, 0, 0);
            if (ks < 18) pb[ks % 6] = *(const bf16x8*)(fb1 + (ks + 6) * 512);
        }

        // ---- exp + P->LDS for half 1 ----
        {
            const int mloc = 128 + w * 16 + l16;         // 128..255
            const bool ok  = (m0 + mloc) < MEMN;
#pragma unroll
            for (int r = 0; r < 4; ++r) {
                float p0 = ok ? __expf(s10[r] * SCALE) : 0.f;
                const int qa = quad * 4 + r;
                lsum[0][r] += p0;
                Ps[qa * 256 + (((mloc >> 3) ^ (qa & 7)) << 3) + (mloc & 7)] = f2bf(p0);
                float p1 = ok ? __expf(s11[r] * SCALE) : 0.f;
                const int qb = 16 + quad * 4 + r;
                lsum[1][r] += p1;
                Ps[qb * 256 + (((mloc >> 3) ^ (qb & 7)) << 3) + (mloc & 7)] = f2bf(p1);
            }
        }

        __syncthreads();   // barrier B: Ps complete

        // ---- phase 2: O += P * Mem; depth-2 register prefetch of B-frags ----
        const unsigned short* msp = memS + ((size_t)(6 * w) * 320 + mc0) * 512 + fr;
        bf16x8 cb[2][6];
#pragma unroll
        for (int nt = 0; nt < 6; ++nt) {
            cb[0][nt] = *(const bf16x8*)(msp + (size_t)nt * 163840);
            cb[1][nt] = *(const bf16x8*)(msp + (size_t)nt * 163840 + 512);
        }

        {
            const int xp0 = (quad ^ xsw) << 3;
            bf16x8 pa0 = *(const bf16x8*)&Ps[l16 * 256 + xp0];
            bf16x8 pa1 = *(const bf16x8*)&Ps[(16 + l16) * 256 + xp0];
#pragma unroll
            for (int ks = 0; ks < 8; ++ks) {
                const int kc  = ks * 32;
                const int nkp = (ks < 7) ? kc + 32 : 0;
                const int xp = (((nkp >> 3) + quad) ^ xsw) << 3;
                bf16x8 npa0 = *(const bf16x8*)&Ps[l16 * 256 + xp];
                bf16x8 npa1 = *(const bf16x8*)&Ps[(16 + l16) * 256 + xp];
                const bool dopf = (ks < 6);
#pragma unroll
                for (int nt = 0; nt < 6; ++nt) {
                    oacc[0][nt] = __builtin_amdgcn_mfma_f32_16x16x32_bf16(pa0, cb[ks & 1][nt], oacc[0][nt], 0, 0, 0);
                    oacc[1][nt] = __builtin_amdgcn_mfma_f32_16x16x32_bf16(pa1, cb[ks & 1][nt], oacc[1][nt], 0, 0, 0);
                    if (dopf) cb[ks & 1][nt] = *(const bf16x8*)(msp + (size_t)nt * 163840 + (ks + 2) * 512);
                }
                pa0 = npa0; pa1 = npa1;
            }
        }
    }

    // ---- epilogue: atomically combine O and L across splits ----
#pragma unroll
    for (int qt = 0; qt < 2; ++qt)
#pragma unroll
        for (int nt = 0; nt < 6; ++nt)
#pragma unroll
            for (int r = 0; r < 4; ++r)
                __hip_atomic_fetch_add(
                    &retrRaw[(size_t)(q0 + qt * 16 + quad * 4 + r) * DIM + dbase + nt * 16 + l16],
                    oacc[qt][nt][r], __ATOMIC_RELAXED, __HIP_MEMORY_SCOPE_AGENT);

#pragma unroll
    for (int qt = 0; qt < 2; ++qt)
#pragma unroll
        for (int r = 0; r < 4; ++r) {
            float v = lsum[qt][r];
#pragma unroll
            for (int off = 1; off < 16; off <<= 1) v += __shfl_xor(v, off);
            if (l16 == 0)
                __hip_atomic_fetch_add(&Lvec[q0 + qt * 16 + quad * 4 + r], v,
                                       __ATOMIC_RELAXED, __HIP_MEMORY_SCOPE_AGENT);
        }
}

// ---------------------------------------------------------------------------
// Normalize retrieved, compute gate, build XRb = bf16([cs + g*r | r]).
// ---------------------------------------------------------------------------
__global__ __launch_bounds__(256)
void finalize_xr(const float* __restrict__ retrRaw, const float* __restrict__ Lvec,
                 const float* __restrict__ cs, const float* __restrict__ gw,
                 const float* __restrict__ gb, unsigned short* __restrict__ XRb)
{
    const int lane = threadIdx.x & 63;
    const int row  = blockIdx.x * 4 + (threadIdx.x >> 6);
    const float rl = 1.0f / Lvec[row];
    const float* rr = retrRaw + (size_t)row * DIM;
    const float* cr = cs + (size_t)row * DIM;

    float4 rv[3], cv[3];
    float d = 0.f;
#pragma unroll
    for (int i = 0; i < 3; ++i) {
        const int c4 = i * 256 + lane * 4;
        float4 r = *(const float4*)&rr[c4];
        r.x *= rl; r.y *= rl; r.z *= rl; r.w *= rl;
        float4 c = *(const float4*)&cr[c4];
        float4 g1 = *(const float4*)&gw[c4];
        float4 g2 = *(const float4*)&gw[DIM + c4];
        d += c.x * g1.x + c.y * g1.y + c.z * g1.z + c.w * g1.w;
        d += r.x * g2.x + r.y * g2.y + r.z * g2.z + r.w * g2.w;
        rv[i] = r; cv[i] = c;
    }
#pragma unroll
    for (int off = 32; off > 0; off >>= 1) d += __shfl_xor(d, off);
    d += gb[0];
    const float g = 1.0f / (1.0f + __expf(-d));

    unsigned short* xb = XRb + (size_t)row * 1536;
#pragma unroll
    for (int i = 0; i < 3; ++i) {
        const int c4 = i * 256 + lane * 4;
        ushort4 xo, ro;
        xo.x = f2bf(cv[i].x + g * rv[i].x); xo.y = f2bf(cv[i].y + g * rv[i].y);
        xo.z = f2bf(cv[i].z + g * rv[i].z); xo.w = f2bf(cv[i].w + g * rv[i].w);
        ro.x = f2bf(rv[i].x); ro.y = f2bf(rv[i].y);
        ro.z = f2bf(rv[i].z); ro.w = f2bf(rv[i].w);
        *(ushort4*)&xb[c4] = xo;
        *(ushort4*)&xb[DIM + c4] = ro;
    }
}

// ---------------------------------------------------------------------------
// MFMA GEMM: C[M x 768] = A[M x K](bf16) @ WT[768 x K](bf16, [n][k]) + bias.
// ---------------------------------------------------------------------------
template <int K, int ACT>
__global__ __launch_bounds__(256, 2)
void gemm_mfma(const unsigned short* __restrict__ A, const unsigned short* __restrict__ WT,
               const float* __restrict__ bias, const float* __restrict__ gamma,
               const float* __restrict__ beta, void* __restrict__ outv)
{
    __shared__ __align__(16) unsigned short As[16 * 256];   // 8 KB, xor-swizzled
    __shared__ float red[2][4][16];

    const int tid  = threadIdx.x;
    const int w    = tid >> 6;
    const int lane = tid & 63;
    const int quad = lane >> 4;
    const int l16  = lane & 15;
    const int row0 = blockIdx.x * 16;
    const int nbase = w * 192;
    const int xsw3 = l16 & 7;

    f32x4 acc[12];
#pragma unroll
    for (int nt = 0; nt < 12; ++nt) acc[nt] = (f32x4){0.f, 0.f, 0.f, 0.f};

    bf16x8 b[12];
#pragma unroll
    for (int nt = 0; nt < 12; ++nt)
        b[nt] = *(const bf16x8*)&WT[(size_t)(nbase + nt * 16 + l16) * K + quad * 8];

    for (int ch = 0; ch < K / 256; ++ch) {
        const int kc0 = ch * 256;
        __syncthreads();
#pragma unroll
        for (int i = 0; i < 2; ++i) {
            const int f = tid + i * 256;
            const int r = f >> 5, kb8 = f & 31;
            *(uint4*)&As[r * 256 + ((kb8 ^ (r & 7)) << 3)] =
                *(const uint4*)&A[(size_t)(row0 + r) * K + kc0 + kb8 * 8];
        }
        __syncthreads();
#pragma unroll
        for (int ks = 0; ks < 8; ++ks) {
            const int kc = ks * 32;
            bf16x8 af = *(const bf16x8*)&As[l16 * 256 + ((((kc >> 3) + quad) ^ xsw3) << 3)];
            int gn = kc0 + kc + 32;
            if (gn >= K) gn = 0;                      // dummy wrap (harmless)
#pragma unroll
            for (int nt = 0; nt < 12; ++nt) {
                acc[nt] = __builtin_amdgcn_mfma_f32_16x16x32_bf16(af, b[nt], acc[nt], 0, 0, 0);
                b[nt] = *(const bf16x8*)&WT[(size_t)(nbase + nt * 16 + l16) * K + gn + quad * 8];
            }
        }
    }

    float bv[12];
#pragma unroll
    for (int nt = 0; nt < 12; ++nt) bv[nt] = bias[nbase + nt * 16 + l16];

    if (ACT == 0) {
        unsigned short* out = (unsigned short*)outv;
#pragma unroll
        for (int nt = 0; nt < 12; ++nt)
#pragma unroll
            for (int r = 0; r < 4; ++r) {
                const int row = row0 + quad * 4 + r;
                float v = acc[nt][r] + bv[nt];
                v = 0.5f * v * (1.0f + erff(v * 0.7071067811865476f));
                out[(size_t)row * DIM + nbase + nt * 16 + l16] = f2bf(v);
            }
    } else {
        float* out = (float*)outv;
        float v[12][4];
        float s1[4] = {0.f, 0.f, 0.f, 0.f}, s2[4] = {0.f, 0.f, 0.f, 0.f};
#pragma unroll
        for (int nt = 0; nt < 12; ++nt)
#pragma unroll
            for (int r = 0; r < 4; ++r) {
                float t = acc[nt][r] + bv[nt];
                v[nt][r] = t;
                s1[r] += t;
                s2[r] += t * t;
            }
#pragma unroll
        for (int r = 0; r < 4; ++r) {
#pragma unroll
            for (int off = 1; off < 16; off <<= 1) {
                s1[r] += __shfl_xor(s1[r], off);
                s2[r] += __shfl_xor(s2[r], off);
            }
            if (l16 == 0) {
                red[0][w][quad * 4 + r] = s1[r];
                red[1][w][quad * 4 + r] = s2[r];
            }
        }
        __syncthreads();
#pragma unroll
        for (int r = 0; r < 4; ++r) {
            const int rl16 = quad * 4 + r;
            const float t1 = red[0][0][rl16] + red[0][1][rl16] + red[0][2][rl16] + red[0][3][rl16];
            const float t2 = red[1][0][rl16] + red[1][1][rl16] + red[1][2][rl16] + red[1][3][rl16];
            const float mu  = t1 * (1.0f / 768.0f);
            const float var = fmaxf(t2 * (1.0f / 768.0f) - mu * mu, 0.f);
            const float rs  = rsqrtf(var + 1e-5f);
            const int row = row0 + rl16;
#pragma unroll
            for (int nt = 0; nt < 12; ++nt) {
                const int col = nbase + nt * 16 + l16;
                out[(size_t)row * DIM + col] = (v[nt][r] - mu) * rs * gamma[col] + beta[col];
            }
        }
    }
}

// ---------------------------------------------------------------------------
extern "C" void kernel_launch(void* const* d_in, const int* in_sizes, int n_in,
                              void* d_out, int out_size, void* d_ws, size_t ws_size,
                              hipStream_t stream)
{
    const float* cs  = (const float*)d_in[0];
    const float* mem = (const float*)d_in[1];
    const float* gw  = (const float*)d_in[2];
    const float* gb  = (const float*)d_in[3];
    const float* fw1 = (const float*)d_in[4];
    const float* fb1 = (const float*)d_in[5];
    const float* fw2 = (const float*)d_in[6];
    const float* fb2 = (const float*)d_in[7];
    const float* gam = (const float*)d_in[8];
    const float* bet = (const float*)d_in[9];
    float* out = (float*)d_out;

    char* ws = (char*)d_ws;
    unsigned short* memF = (unsigned short*)ws;                 // 15,728,640
    unsigned short* memS = (unsigned short*)(ws + 15728640);    // 15,728,640
    unsigned short* qH   = (unsigned short*)(ws + 31457280);    // 12,582,912
    float*          retr = (float*)(ws + 44040192);             // 25,165,824
    float*          Lvec = (float*)(ws + 69206016);             // 32,768
    unsigned short* w12T = (unsigned short*)(ws + 69238784);    // 2,359,296
    unsigned short* w2T  = (unsigned short*)(ws + 71598080);    // 1,179,648
    unsigned short* XRb  = (unsigned short*)ws;                 // alias memF+memS
    unsigned short* hb   = qH;                                  // alias qH

    hipMemsetAsync(retr, 0, 25165824 + 32768, stream);

    cvt_memF<<<MEMP / 16, 256, 0, stream>>>(mem, memF);
    cvt_qH<<<(N_TOK * DIM) / (256 * 4), 256, 0, stream>>>(cs, qH);
    cvt_memS<<<dim3(MEMP / 32, DIM / 64), 256, 0, stream>>>(mem, memS);
    prep_w12T<<<dim3(48, 24), 256, 0, stream>>>(fw1, w12T);
    prep_w2T<<<dim3(24, 24), 256, 0, stream>>>(fw2, w2T);

    attn_mfma<<<dim3(N_TOK / TQ, NSPLIT), 512, 0, stream>>>(qH, memF, memS, retr, Lvec);
    finalize_xr<<<N_TOK / 4, 256, 0, stream>>>(retr, Lvec, cs, gw, gb, XRb);
    gemm_mfma<1536, 0><<<N_TOK / 16, 256, 0, stream>>>(XRb, w12T, fb1, nullptr, nullptr, hb);
    gemm_mfma<768, 1><<<N_TOK / 16, 256, 0, stream>>>(hb, w2T, fb2, gam, bet, out);
}

// Round 6
// 1070.603 us; speedup vs baseline: 1.1568x; 1.1568x over previous
//
#include <hip/hip_runtime.h>
#include <math.h>

#define N_TOK 8192
#define DIM   768
#define MEMN  10000
#define MEMP  10240            // padded to 40*256
#define TQ    32
#define TM    256
#define NSPLIT 2
#define TILES_PER_SPLIT 20

constexpr float SCALE = 0.036084391824351615f;  // 1/sqrt(768)

typedef short bf16x8 __attribute__((ext_vector_type(8)));
typedef float f32x4  __attribute__((ext_vector_type(4)));

__device__ __forceinline__ unsigned short f2bf(float f) {
    unsigned u = __float_as_uint(f);
    unsigned r = (u + 0x7fffu + ((u >> 16) & 1u)) >> 16;   // RTN-even
    return (unsigned short)r;
}

// ---------------------------------------------------------------------------
// memF: fragment-linear bf16 layout of mem for phase 1 (QK^T B-operand).
// slot(mb, kc, l16, quad, j) = mem[mb*16 + l16][kc*32 + quad*8 + j]
// offset (ushorts) = (mb*24 + kc)*512 + (l16*4 + quad)*8
// ---------------------------------------------------------------------------
__global__ void cvt_memF(const float* __restrict__ mem, unsigned short* __restrict__ dst)
{
    const int mb = blockIdx.x;                       // 0..639
    const bool zero = (mb >= MEMN / 16);             // 625 exact blocks valid
#pragma unroll
    for (int it = 0; it < 6; ++it) {
        const int s   = it * 256 + threadIdx.x;      // 0..1535
        const int kc  = s >> 6;
        const int r   = s & 63;
        const int l16 = r >> 2, q = r & 3;
        unsigned short o[8];
        if (!zero) {
            const float* src = &mem[(size_t)(mb * 16 + l16) * DIM + kc * 32 + q * 8];
            float4 v0 = *(const float4*)src;
            float4 v1 = *(const float4*)(src + 4);
            o[0] = f2bf(v0.x); o[1] = f2bf(v0.y); o[2] = f2bf(v0.z); o[3] = f2bf(v0.w);
            o[4] = f2bf(v1.x); o[5] = f2bf(v1.y); o[6] = f2bf(v1.z); o[7] = f2bf(v1.w);
        } else {
#pragma unroll
            for (int j = 0; j < 8; ++j) o[j] = 0;
        }
        *(uint4*)&dst[((size_t)mb * 24 + kc) * 512 + r * 8] = *(const uint4*)o;
    }
}

// ---------------------------------------------------------------------------
// Q fp32 -> bf16 (row-major, same layout)
// ---------------------------------------------------------------------------
__global__ void cvt_qH(const float* __restrict__ q, unsigned short* __restrict__ dst)
{
    const size_t i = ((size_t)blockIdx.x * 256 + threadIdx.x) * 4;
    float4 v = *(const float4*)&q[i];
    ushort4 o;
    o.x = f2bf(v.x); o.y = f2bf(v.y); o.z = f2bf(v.z); o.w = f2bf(v.w);
    *(ushort4*)&dst[i] = o;
}

// ---------------------------------------------------------------------------
// memS: fragment-linear transposed layout for phase 2 (PV B-operand).
// slot(db, mc, l16, quad, j) = mem[mc*32 + quad*8 + j][db*16 + l16]  (0 if m>=10000)
// offset (ushorts) = (db*320 + mc)*512 + (l16*4 + quad)*8
// ---------------------------------------------------------------------------
__global__ void cvt_memS(const float* __restrict__ mem, unsigned short* __restrict__ dst)
{
    __shared__ float T[32][65];
    const int mc = blockIdx.x;              // m-chunk of 32
    const int d0 = blockIdx.y * 64;         // d base
    const int tx = threadIdx.x & 63;        // d within 64
    const int ty = threadIdx.x >> 6;        // 0..3
#pragma unroll
    for (int i = 0; i < 8; ++i) {
        const int row = ty + 4 * i;                  // 0..31
        const int m   = mc * 32 + row;
        T[row][tx] = (m < MEMN) ? mem[(size_t)m * DIM + d0 + tx] : 0.f;
    }
    __syncthreads();
    const int dbl = threadIdx.x >> 6;       // local 16-d block 0..3
    const int r   = threadIdx.x & 63;
    const int l16 = r >> 2, q = r & 3;
    unsigned short o[8];
#pragma unroll
    for (int j = 0; j < 8; ++j) o[j] = f2bf(T[q * 8 + j][dbl * 16 + l16]);
    *(uint4*)&dst[((size_t)(d0 / 16 + dbl) * 320 + mc) * 512 + r * 8] = *(const uint4*)o;
}

// ---------------------------------------------------------------------------
// W12T bf16 [768 n][1536 k]
// ---------------------------------------------------------------------------
__global__ void prep_w12T(const float* __restrict__ w1, unsigned short* __restrict__ wt)
{
    __shared__ float T[32][33];
    const int kb = blockIdx.x * 32, nb = blockIdx.y * 32;
    const int tx = threadIdx.x & 31, ty = threadIdx.x >> 5;
#pragma unroll
    for (int i = 0; i < 4; ++i) {
        int k = kb + ty + 8 * i;
        float v = w1[(size_t)(768 + k) * DIM + nb + tx];
        if (kb < 768) v += w1[(size_t)k * DIM + nb + tx];
        T[ty + 8 * i][tx] = v;
    }
    __syncthreads();
#pragma unroll
    for (int i = 0; i < 4; ++i) {
        int n = nb + ty + 8 * i;
        wt[(size_t)n * 1536 + kb + tx] = f2bf(T[tx][ty + 8 * i]);
    }
}

// ---------------------------------------------------------------------------
// W2T bf16 [768 n][768 k] = w2[k][n]
// ---------------------------------------------------------------------------
__global__ void prep_w2T(const float* __restrict__ w2, unsigned short* __restrict__ wt)
{
    __shared__ float T[32][33];
    const int kb = blockIdx.x * 32, nb = blockIdx.y * 32;
    const int tx = threadIdx.x & 31, ty = threadIdx.x >> 5;
#pragma unroll
    for (int i = 0; i < 4; ++i)
        T[ty + 8 * i][tx] = w2[(size_t)(kb + ty + 8 * i) * DIM + nb + tx];
    __syncthreads();
#pragma unroll
    for (int i = 0; i < 4; ++i)
        wt[(size_t)(nb + ty + 8 * i) * DIM + kb + tx] = f2bf(T[tx][ty + 8 * i]);
}

// ---------------------------------------------------------------------------
// Fused MFMA attention. Round-13:
//  - main loop EXACTLY round-2 (762 us verified, no spill; 3 attempts to buy
//    pipeline depth with VGPRs all spilled -- the 128-reg budget has no slack).
//  - epilogue: PLAIN=1 replaces 25.2M f32 atomic RMWs (~3 us/M measured via
//    the NSPLIT 2/4/8 sweep => ~75 us here) with plain stores to per-split
//    buffers retr[2][][] / Lvec[2][]; L reduced across the block's 8 waves in
//    1 KB LDS first. finalize_xr sums the two partials; memset eliminated.
//  - PLAIN=0 fallback (atomic path, old layout) if workspace < ~98 MB.
// ---------------------------------------------------------------------------
template <int PLAIN>
__global__ __launch_bounds__(512, 4)
void attn_mfma(const unsigned short* __restrict__ qH, const unsigned short* __restrict__ memF,
               const unsigned short* __restrict__ memS,
               float* __restrict__ retrRaw, float* __restrict__ Lvec)
{
    __shared__ __align__(16) unsigned short Qs[32 * 768];   // 48 KB, xor-swizzled
    __shared__ __align__(16) unsigned short Ps[32 * 256];   // 16 KB, xor-swizzled
    __shared__ float Lred[8][32];                           // 1 KB, L block-reduce

    const int tid    = threadIdx.x;
    const int w      = tid >> 6;         // wave 0..7
    const int lane   = tid & 63;
    const int quad   = lane >> 4;        // 0..3
    const int l16    = lane & 15;
    const int fr     = ((l16 << 2) | quad) << 3;   // fragment-linear lane offset (ushorts)

    const int lb    = blockIdx.x + gridDim.x * blockIdx.y;   // 0..511
    const int split = (lb >> 2) & 1;
    const int qi    = ((lb >> 3) << 2) | (lb & 3);           // 0..255
    const int q0    = qi * TQ;

    const int dbase  = w * 96;           // phase-2 d-strip per wave
    const int mstrip = w * 32;           // phase-1 m-strip per wave

    // ---- stage Q tile (bf16, swizzled) once ----
    {
        const int qr  = tid >> 4;            // 0..31
        const int db0 = tid & 15;
        const unsigned short* src = qH + (size_t)(q0 + qr) * DIM;
        const int sw = qr & 7;
#pragma unroll
        for (int i = 0; i < 6; ++i) {
            int db = db0 + i * 16;           // 0..95 (blocks of 8 bf16)
            uint4 v = *(const uint4*)&src[db * 8];
            *(uint4*)&Qs[qr * 768 + ((db ^ sw) << 3)] = v;
        }
    }
    __syncthreads();

    f32x4 oacc[2][6];
#pragma unroll
    for (int a = 0; a < 2; ++a)
#pragma unroll
        for (int b = 0; b < 6; ++b) oacc[a][b] = (f32x4){0.f, 0.f, 0.f, 0.f};
    float lsum[2][4] = {{0.f, 0.f, 0.f, 0.f}, {0.f, 0.f, 0.f, 0.f}};

    const int xsw = l16 & 7;

    for (int st = 0; st < TILES_PER_SPLIT; ++st) {
        const int m0  = (split * TILES_PER_SPLIT + st) * TM;
        const int mc0 = m0 >> 5;                          // m-chunk base for phase 2

        // ---- phase 1: S[32 x 256]; wave w covers m-strip mstrip..+32 ----
        f32x4 sacc[2][2];
#pragma unroll
        for (int a = 0; a < 2; ++a)
#pragma unroll
            for (int b = 0; b < 2; ++b) sacc[a][b] = (f32x4){0.f, 0.f, 0.f, 0.f};

        const unsigned short* fb0 = memF + ((size_t)(m0 >> 4) + 2 * w) * 12288 + fr;
        const unsigned short* fb1 = fb0 + 12288;

        bf16x8 b0 = *(const bf16x8*)(fb0);
        bf16x8 b1 = *(const bf16x8*)(fb1);
        {
            const int xq0 = (quad ^ xsw) << 3;
            bf16x8 a0 = *(const bf16x8*)&Qs[l16 * 768 + xq0];
            bf16x8 a1 = *(const bf16x8*)&Qs[(16 + l16) * 768 + xq0];
#pragma unroll
            for (int ks = 0; ks < 23; ++ks) {
                bf16x8 nb0 = *(const bf16x8*)(fb0 + (ks + 1) * 512);
                bf16x8 nb1 = *(const bf16x8*)(fb1 + (ks + 1) * 512);
                const int xq = ((((ks + 1) << 2) + quad) ^ xsw) << 3;
                bf16x8 na0 = *(const bf16x8*)&Qs[l16 * 768 + xq];
                bf16x8 na1 = *(const bf16x8*)&Qs[(16 + l16) * 768 + xq];
                sacc[0][0] = __builtin_amdgcn_mfma_f32_16x16x32_bf16(a0, b0, sacc[0][0], 0, 0, 0);
                sacc[1][0] = __builtin_amdgcn_mfma_f32_16x16x32_bf16(a1, b0, sacc[1][0], 0, 0, 0);
                sacc[0][1] = __builtin_amdgcn_mfma_f32_16x16x32_bf16(a0, b1, sacc[0][1], 0, 0, 0);
                sacc[1][1] = __builtin_amdgcn_mfma_f32_16x16x32_bf16(a1, b1, sacc[1][1], 0, 0, 0);
                a0 = na0; a1 = na1; b0 = nb0; b1 = nb1;
            }
            sacc[0][0] = __builtin_amdgcn_mfma_f32_16x16x32_bf16(a0, b0, sacc[0][0], 0, 0, 0);
            sacc[1][0] = __builtin_amdgcn_mfma_f32_16x16x32_bf16(a1, b0, sacc[1][0], 0, 0, 0);
            sacc[0][1] = __builtin_amdgcn_mfma_f32_16x16x32_bf16(a0, b1, sacc[0][1], 0, 0, 0);
            sacc[1][1] = __builtin_amdgcn_mfma_f32_16x16x32_bf16(a1, b1, sacc[1][1], 0, 0, 0);
        }

        __syncthreads();   // barrier A

        // ---- exp + P->LDS (bf16, swizzled) + row-sum accumulation ----
#pragma unroll
        for (int qt = 0; qt < 2; ++qt)
#pragma unroll
            for (int mt = 0; mt < 2; ++mt) {
                const int mloc = mstrip + mt * 16 + l16;      // 0..255
                const bool ok  = (m0 + mloc) < MEMN;
#pragma unroll
                for (int r = 0; r < 4; ++r) {
                    float p = ok ? __expf(sacc[qt][mt][r] * SCALE) : 0.f;
                    const int q = qt * 16 + quad * 4 + r;
                    lsum[qt][r] += p;
                    Ps[q * 256 + (((mloc >> 3) ^ (q & 7)) << 3) + (mloc & 7)] = f2bf(p);
                }
            }

        __syncthreads();   // barrier B

        // ---- phase 2: O += P * Mem; depth-2 register prefetch of B-frags ----
        const unsigned short* msp = memS + ((size_t)(6 * w) * 320 + mc0) * 512 + fr;
        bf16x8 cb[2][6];
#pragma unroll
        for (int nt = 0; nt < 6; ++nt) {
            cb[0][nt] = *(const bf16x8*)(msp + (size_t)nt * 163840);
            cb[1][nt] = *(const bf16x8*)(msp + (size_t)nt * 163840 + 512);
        }

        {
            const int xp0 = (quad ^ xsw) << 3;
            bf16x8 pa0 = *(const bf16x8*)&Ps[l16 * 256 + xp0];
            bf16x8 pa1 = *(const bf16x8*)&Ps[(16 + l16) * 256 + xp0];
#pragma unroll
            for (int ks = 0; ks < 8; ++ks) {
                const int kc  = ks * 32;
                const int nkp = (ks < 7) ? kc + 32 : 0;
                const int xp = (((nkp >> 3) + quad) ^ xsw) << 3;
                bf16x8 npa0 = *(const bf16x8*)&Ps[l16 * 256 + xp];
                bf16x8 npa1 = *(const bf16x8*)&Ps[(16 + l16) * 256 + xp];
                const bool dopf = (ks < 6);
#pragma unroll
                for (int nt = 0; nt < 6; ++nt) {
                    oacc[0][nt] = __builtin_amdgcn_mfma_f32_16x16x32_bf16(pa0, cb[ks & 1][nt], oacc[0][nt], 0, 0, 0);
                    oacc[1][nt] = __builtin_amdgcn_mfma_f32_16x16x32_bf16(pa1, cb[ks & 1][nt], oacc[1][nt], 0, 0, 0);
                    if (dopf) cb[ks & 1][nt] = *(const bf16x8*)(msp + (size_t)nt * 163840 + (ks + 2) * 512);
                }
                pa0 = npa0; pa1 = npa1;
            }
        }
    }

    // ---- epilogue: combine O and L across splits ----
    float* ob = retrRaw + (PLAIN ? (size_t)split * ((size_t)N_TOK * DIM) : (size_t)0);
#pragma unroll
    for (int qt = 0; qt < 2; ++qt)
#pragma unroll
        for (int nt = 0; nt < 6; ++nt)
#pragma unroll
            for (int r = 0; r < 4; ++r) {
                const size_t idx = (size_t)(q0 + qt * 16 + quad * 4 + r) * DIM + dbase + nt * 16 + l16;
                if (PLAIN)
                    ob[idx] = oacc[qt][nt][r];
                else
                    __hip_atomic_fetch_add(&ob[idx], oacc[qt][nt][r],
                                           __ATOMIC_RELAXED, __HIP_MEMORY_SCOPE_AGENT);
            }

#pragma unroll
    for (int qt = 0; qt < 2; ++qt)
#pragma unroll
        for (int r = 0; r < 4; ++r) {
            float v = lsum[qt][r];
#pragma unroll
            for (int off = 1; off < 16; off <<= 1) v += __shfl_xor(v, off);
            if (l16 == 0) {
                if (PLAIN)
                    Lred[w][qt * 16 + quad * 4 + r] = v;
                else
                    __hip_atomic_fetch_add(&Lvec[q0 + qt * 16 + quad * 4 + r], v,
                                           __ATOMIC_RELAXED, __HIP_MEMORY_SCOPE_AGENT);
            }
        }
    if (PLAIN) {
        __syncthreads();
        if (tid < 32) {
            float s = 0.f;
#pragma unroll
            for (int ww = 0; ww < 8; ++ww) s += Lred[ww][tid];
            Lvec[(size_t)split * N_TOK + q0 + tid] = s;
        }
    }
}

// ---------------------------------------------------------------------------
// Normalize retrieved, compute gate, build XRb = bf16([cs + g*r | r]).
// PLAIN=1: retrRaw/Lvec hold 2 split-partials, summed here.
// ---------------------------------------------------------------------------
template <int PLAIN>
__global__ __launch_bounds__(256)
void finalize_xr(const float* __restrict__ retrRaw, const float* __restrict__ Lvec,
                 const float* __restrict__ cs, const float* __restrict__ gw,
                 const float* __restrict__ gb, unsigned short* __restrict__ XRb)
{
    const int lane = threadIdx.x & 63;
    const int row  = blockIdx.x * 4 + (threadIdx.x >> 6);
    const float lv = PLAIN ? (Lvec[row] + Lvec[N_TOK + row]) : Lvec[row];
    const float rl = 1.0f / lv;
    const float* rr  = retrRaw + (size_t)row * DIM;
    const float* rr1 = retrRaw + (size_t)N_TOK * DIM + (size_t)row * DIM;
    const float* cr = cs + (size_t)row * DIM;

    float4 rv[3], cv[3];
    float d = 0.f;
#pragma unroll
    for (int i = 0; i < 3; ++i) {
        const int c4 = i * 256 + lane * 4;
        float4 r = *(const float4*)&rr[c4];
        if (PLAIN) {
            float4 r1 = *(const float4*)&rr1[c4];
            r.x += r1.x; r.y += r1.y; r.z += r1.z; r.w += r1.w;
        }
        r.x *= rl; r.y *= rl; r.z *= rl; r.w *= rl;
        float4 c = *(const float4*)&cr[c4];
        float4 g1 = *(const float4*)&gw[c4];
        float4 g2 = *(const float4*)&gw[DIM + c4];
        d += c.x * g1.x + c.y * g1.y + c.z * g1.z + c.w * g1.w;
        d += r.x * g2.x + r.y * g2.y + r.z * g2.z + r.w * g2.w;
        rv[i] = r; cv[i] = c;
    }
#pragma unroll
    for (int off = 32; off > 0; off >>= 1) d += __shfl_xor(d, off);
    d += gb[0];
    const float g = 1.0f / (1.0f + __expf(-d));

    unsigned short* xb = XRb + (size_t)row * 1536;
#pragma unroll
    for (int i = 0; i < 3; ++i) {
        const int c4 = i * 256 + lane * 4;
        ushort4 xo, ro;
        xo.x = f2bf(cv[i].x + g * rv[i].x); xo.y = f2bf(cv[i].y + g * rv[i].y);
        xo.z = f2bf(cv[i].z + g * rv[i].z); xo.w = f2bf(cv[i].w + g * rv[i].w);
        ro.x = f2bf(rv[i].x); ro.y = f2bf(rv[i].y);
        ro.z = f2bf(rv[i].z); ro.w = f2bf(rv[i].w);
        *(ushort4*)&xb[c4] = xo;
        *(ushort4*)&xb[DIM + c4] = ro;
    }
}

// ---------------------------------------------------------------------------
// MFMA GEMM: C[M x 768] = A[M x K](bf16) @ WT[768 x K](bf16, [n][k]) + bias.
// ---------------------------------------------------------------------------
template <int K, int ACT>
__global__ __launch_bounds__(256, 2)
void gemm_mfma(const unsigned short* __restrict__ A, const unsigned short* __restrict__ WT,
               const float* __restrict__ bias, const float* __restrict__ gamma,
               const float* __restrict__ beta, void* __restrict__ outv)
{
    __shared__ __align__(16) unsigned short As[16 * 256];   // 8 KB, xor-swizzled
    __shared__ float red[2][4][16];

    const int tid  = threadIdx.x;
    const int w    = tid >> 6;
    const int lane = tid & 63;
    const int quad = lane >> 4;
    const int l16  = lane & 15;
    const int row0 = blockIdx.x * 16;
    const int nbase = w * 192;
    const int xsw3 = l16 & 7;

    f32x4 acc[12];
#pragma unroll
    for (int nt = 0; nt < 12; ++nt) acc[nt] = (f32x4){0.f, 0.f, 0.f, 0.f};

    bf16x8 b[12];
#pragma unroll
    for (int nt = 0; nt < 12; ++nt)
        b[nt] = *(const bf16x8*)&WT[(size_t)(nbase + nt * 16 + l16) * K + quad * 8];

    for (int ch = 0; ch < K / 256; ++ch) {
        const int kc0 = ch * 256;
        __syncthreads();
#pragma unroll
        for (int i = 0; i < 2; ++i) {
            const int f = tid + i * 256;
            const int r = f >> 5, kb8 = f & 31;
            *(uint4*)&As[r * 256 + ((kb8 ^ (r & 7)) << 3)] =
                *(const uint4*)&A[(size_t)(row0 + r) * K + kc0 + kb8 * 8];
        }
        __syncthreads();
#pragma unroll
        for (int ks = 0; ks < 8; ++ks) {
            const int kc = ks * 32;
            bf16x8 af = *(const bf16x8*)&As[l16 * 256 + ((((kc >> 3) + quad) ^ xsw3) << 3)];
            int gn = kc0 + kc + 32;
            if (gn >= K) gn = 0;                      // dummy wrap (harmless)
#pragma unroll
            for (int nt = 0; nt < 12; ++nt) {
                acc[nt] = __builtin_amdgcn_mfma_f32_16x16x32_bf16(af, b[nt], acc[nt], 0, 0, 0);
                b[nt] = *(const bf16x8*)&WT[(size_t)(nbase + nt * 16 + l16) * K + gn + quad * 8];
            }
        }
    }

    float bv[12];
#pragma unroll
    for (int nt = 0; nt < 12; ++nt) bv[nt] = bias[nbase + nt * 16 + l16];

    if (ACT == 0) {
        unsigned short* out = (unsigned short*)outv;
#pragma unroll
        for (int nt = 0; nt < 12; ++nt)
#pragma unroll
            for (int r = 0; r < 4; ++r) {
                const int row = row0 + quad * 4 + r;
                float v = acc[nt][r] + bv[nt];
                v = 0.5f * v * (1.0f + erff(v * 0.7071067811865476f));
                out[(size_t)row * DIM + nbase + nt * 16 + l16] = f2bf(v);
            }
    } else {
        float* out = (float*)outv;
        float v[12][4];
        float s1[4] = {0.f, 0.f, 0.f, 0.f}, s2[4] = {0.f, 0.f, 0.f, 0.f};
#pragma unroll
        for (int nt = 0; nt < 12; ++nt)
#pragma unroll
            for (int r = 0; r < 4; ++r) {
                float t = acc[nt][r] + bv[nt];
                v[nt][r] = t;
                s1[r] += t;
                s2[r] += t * t;
            }
#pragma unroll
        for (int r = 0; r < 4; ++r) {
#pragma unroll
            for (int off = 1; off < 16; off <<= 1) {
                s1[r] += __shfl_xor(s1[r], off);
                s2[r] += __shfl_xor(s2[r], off);
            }
            if (l16 == 0) {
                red[0][w][quad * 4 + r] = s1[r];
                red[1][w][quad * 4 + r] = s2[r];
            }
        }
        __syncthreads();
#pragma unroll
        for (int r = 0; r < 4; ++r) {
            const int rl16 = quad * 4 + r;
            const float t1 = red[0][0][rl16] + red[0][1][rl16] + red[0][2][rl16] + red[0][3][rl16];
            const float t2 = red[1][0][rl16] + red[1][1][rl16] + red[1][2][rl16] + red[1][3][rl16];
            const float mu  = t1 * (1.0f / 768.0f);
            const float var = fmaxf(t2 * (1.0f / 768.0f) - mu * mu, 0.f);
            const float rs  = rsqrtf(var + 1e-5f);
            const int row = row0 + rl16;
#pragma unroll
            for (int nt = 0; nt < 12; ++nt) {
                const int col = nbase + nt * 16 + l16;
                out[(size_t)row * DIM + col] = (v[nt][r] - mu) * rs * gamma[col] + beta[col];
            }
        }
    }
}

// ---------------------------------------------------------------------------
extern "C" void kernel_launch(void* const* d_in, const int* in_sizes, int n_in,
                              void* d_out, int out_size, void* d_ws, size_t ws_size,
                              hipStream_t stream)
{
    const float* cs  = (const float*)d_in[0];
    const float* mem = (const float*)d_in[1];
    const float* gw  = (const float*)d_in[2];
    const float* gb  = (const float*)d_in[3];
    const float* fw1 = (const float*)d_in[4];
    const float* fb1 = (const float*)d_in[5];
    const float* fw2 = (const float*)d_in[6];
    const float* fb2 = (const float*)d_in[7];
    const float* gam = (const float*)d_in[8];
    const float* bet = (const float*)d_in[9];
    float* out = (float*)d_out;

    char* ws = (char*)d_ws;
    // Layout A (atomic fallback, ~72.8 MB) / Layout B (plain, ~98 MB):
    const size_t PLAIN_WS = 97976320;
    const bool plain = (ws_size >= PLAIN_WS);

    unsigned short* memF = (unsigned short*)ws;                 // 15,728,640
    unsigned short* memS = (unsigned short*)(ws + 15728640);    // 15,728,640
    unsigned short* qH   = (unsigned short*)(ws + 31457280);    // 12,582,912
    float*          retr = (float*)(ws + 44040192);             // A: 25,165,824 / B: 50,331,648
    float*          Lvec;
    unsigned short* w12T;
    unsigned short* w2T;
    if (plain) {
        Lvec = (float*)(ws + 94371840);            // 65,536 (2 splits)
        w12T = (unsigned short*)(ws + 94437376);   // 2,359,296
        w2T  = (unsigned short*)(ws + 96796672);   // 1,179,648 -> end 97,976,320
    } else {
        Lvec = (float*)(ws + 69206016);            // 32,768
        w12T = (unsigned short*)(ws + 69238784);   // 2,359,296
        w2T  = (unsigned short*)(ws + 71598080);   // 1,179,648 -> end 72,777,728
    }
    unsigned short* XRb  = (unsigned short*)ws;                 // alias memF+memS (dead after attn)
    unsigned short* hb   = qH;                                  // alias qH (dead after attn)

    if (!plain)
        hipMemsetAsync(retr, 0, 25165824 + 32768, stream);      // atomic path needs zeroed accum

    cvt_memF<<<MEMP / 16, 256, 0, stream>>>(mem, memF);
    cvt_qH<<<(N_TOK * DIM) / (256 * 4), 256, 0, stream>>>(cs, qH);
    cvt_memS<<<dim3(MEMP / 32, DIM / 64), 256, 0, stream>>>(mem, memS);
    prep_w12T<<<dim3(48, 24), 256, 0, stream>>>(fw1, w12T);
    prep_w2T<<<dim3(24, 24), 256, 0, stream>>>(fw2, w2T);

    if (plain) {
        attn_mfma<1><<<dim3(N_TOK / TQ, NSPLIT), 512, 0, stream>>>(qH, memF, memS, retr, Lvec);
        finalize_xr<1><<<N_TOK / 4, 256, 0, stream>>>(retr, Lvec, cs, gw, gb, XRb);
    } else {
        attn_mfma<0><<<dim3(N_TOK / TQ, NSPLIT), 512, 0, stream>>>(qH, memF, memS, retr, Lvec);
        finalize_xr<0><<<N_TOK / 4, 256, 0, stream>>>(retr, Lvec, cs, gw, gb, XRb);
    }
    gemm_mfma<1536, 0><<<N_TOK / 16, 256, 0, stream>>>(XRb, w12T, fb1, nullptr, nullptr, hb);
    gemm_mfma<768, 1><<<N_TOK / 16, 256, 0, stream>>>(hb, w2T, fb2, gam, bet, out);
}